// Round 6
// baseline (348.561 us; speedup 1.0000x reference)
//
#include <hip/hip_runtime.h>
#include <hip/hip_bf16.h>
#include <cstddef>

// ---------------------------------------------------------------------------
// MTCNN P-Net forward, NCHW in/out. All three convs on MFMA bf16.
//   x[16,3,720,720] -> (norm folded into w1) conv1(3->10,3x3)+PReLU+maxpool2
//        via MFMA 32x32x16 (9 taps, K=3 real ch)  -> pooled NHWC bf16 (16ch pad)
//     -> conv2(16pad->16,3x3) via MFMA 16x16x32 -> NHWC bf16
//     -> conv3(16->32,3x3)+PReLU via MFMA 32x32x16, fused 1x1 heads + softmax
//   out = concat(reg[16,4,355,355], prob[16,2,355,355]) flat fp32
// ---------------------------------------------------------------------------

#define H1 718
#define PH 359   // pooled spatial
#define H2 357   // conv2 out spatial
#define H3 355   // conv3 out spatial

// workspace layout (float offsets)
#define B1R_OFF 0              // 10 fp32 bias (norm folded in)
#define BW1_OFF 16             // 4608 bf16 = 2304 fl: conv1 B-frags [tap][lane][8]
#define AW2_OFF 2320           // 2560 bf16 = 1280 fl: conv2 A-frags [step][lane][8]
#define BW3_OFF 3600           // 4608 bf16 = 2304 fl: conv3 B-frags [tap][lane][8]
#define P16_OFF 5952           // pooled NHWC bf16 [16,359,359,16] = 16496768 fl
#define C2H_OFF 16502720       // conv2 out NHWC bf16 [16,357,357,16] = 16313472 fl

typedef short bf16x8 __attribute__((ext_vector_type(8)));
typedef float f32x4  __attribute__((ext_vector_type(4)));
typedef float f32x16 __attribute__((ext_vector_type(16)));
typedef unsigned short ushort4v __attribute__((ext_vector_type(4)));

// Build A-frag from one pixel's packed 3ch bf16 (+pad). Slots 4..7 duplicate
// slots 0..3; they hit zero B rows (k>=3 weights are 0) so contribute nothing.
// Union instead of bit_cast / pointer punning (R5 crash suspect).
static __device__ __forceinline__ bf16x8 make_a(uint2 q) {
    union { unsigned int u[4]; bf16x8 v; } c;
    c.u[0] = q.x; c.u[1] = q.y; c.u[2] = q.x; c.u[3] = q.y;
    return c.v;
}

// ---------------------------------------------------------------------------
// Weight repack.
//  - conv1: fold (x-127.5)/128 into w/b. B-frag[tap][lane][j]: n=lane&31(c_out),
//      k=(lane>>5)*8+j; real only k<3 (=ci) && n<10, else 0 -> zero rows
//      annihilate A-frag pad/garbage slots.
//  - conv2: MFMA 16x16x32 A-frags (A=weights, M=c_out), zero-padded ci>=10,tap9.
//  - conv3: MFMA 32x32x16 B-frags (verified R3/R4).
// ---------------------------------------------------------------------------
__global__ void repack_kernel(const float* __restrict__ w1, const float* __restrict__ b1,
                              const float* __restrict__ w2, const float* __restrict__ w3,
                              float* __restrict__ ws) {
    int t = threadIdx.x;
    const float S = 0.0078125f;
    if (t < 10) {
        float s = 0.f;
        for (int i = 0; i < 27; i++) s += w1[t * 27 + i];
        ws[B1R_OFF + t] = b1[t] - 127.5f * S * s;
    }
    unsigned short* bw1 = (unsigned short*)(ws + BW1_OFF);
    for (int e = t; e < 4608; e += blockDim.x) {
        int tap = e >> 9;
        int rem = e & 511;
        int l = rem >> 3, j = rem & 7;
        int n = l & 31, k = ((l >> 5) << 3) + j;
        float v = (k < 3 && n < 10) ? w1[n * 27 + k * 9 + tap] * S : 0.f;
        __hip_bfloat16 h = __float2bfloat16(v);
        bw1[e] = *(unsigned short*)&h;
    }
    unsigned short* aw2 = (unsigned short*)(ws + AW2_OFF);
    for (int e = t; e < 2560; e += blockDim.x) {
        int s = e >> 9;              // K-step 0..4
        int rem = e & 511;
        int l = rem >> 3, j = rem & 7;
        int q = l >> 4, co = l & 15;
        int tap = 2 * s + (q >> 1);
        int ci  = ((q & 1) << 3) + j;
        float v = (tap < 9 && ci < 10) ? w2[co * 90 + ci * 9 + tap] : 0.f;
        __hip_bfloat16 h = __float2bfloat16(v);
        aw2[e] = *(unsigned short*)&h;
    }
    unsigned short* bw3 = (unsigned short*)(ws + BW3_OFF);
    for (int e = t; e < 4608; e += blockDim.x) {
        int tap = e >> 9;
        int rem = e & 511;
        int l = rem >> 3, j = rem & 7;
        int kh = tap / 3, kw = tap % 3;
        int co = l & 31, ci = ((l >> 5) << 3) + j;
        float v = w3[co * 144 + ci * 9 + kh * 3 + kw];
        __hip_bfloat16 h = __float2bfloat16(v);
        bw3[e] = *(unsigned short*)&h;
    }
}

// ---------------------------------------------------------------------------
// Stage 1: norm+conv1+PReLU+maxpool via MFMA 32x32x16 bf16.
// Block (256 thr, 4 waves) covers conv region 64x x 16y -> pooled 32x8.
// LDS: typed uint2 tile [18 rows][68] (66 used) — one pixel's 3ch bf16+pad per
// element; staging is one ds_write_b64/px, A-frag fetch one ds_read_b64.
// 9 taps = 9 MFMA per (row,32px tile); K slots >=3 have zero B weights.
// D (m101): lane&31 = c_out, regs = pixel-x -> both pool directions in-lane.
// PReLU via fmax(v, a*v) (valid for a=0.25<=1).
// grid: (ceil(718/64)=12, ceil(718/16)=45, 16), block 256
// ---------------------------------------------------------------------------
__global__ __launch_bounds__(256)
void conv1_mfma_kernel(const float* __restrict__ x,
                       const float* __restrict__ ws,
                       const float* __restrict__ a1,
                       __hip_bfloat16* __restrict__ p16) {
    __shared__ uint2 st[18][68];     // 9792 B
    int tid = threadIdx.x;
    int wv = tid >> 6;
    int l  = tid & 63;
    int x0 = blockIdx.x * 64;     // conv-x origin
    int y0 = blockIdx.y * 16;     // conv-y origin
    int n  = blockIdx.z;

    // ---- stage 66x18 px (3ch fp32 -> bf16x3 + 0 pad) ----
    for (int e = tid; e < 66 * 18; e += 256) {
        int row = e / 66, xx = e - row * 66;
        int gx = x0 + xx; if (gx > 719) gx = 719;
        int gy = y0 + row; if (gy > 719) gy = 719;
        const float* xp = x + (size_t)n * 1555200 + (size_t)gy * 720 + gx;
        __hip_bfloat16 h0 = __float2bfloat16(xp[0]);
        __hip_bfloat16 h1 = __float2bfloat16(xp[518400]);
        __hip_bfloat16 h2 = __float2bfloat16(xp[1036800]);
        uint2 val;
        val.x = (unsigned int)(*(unsigned short*)&h0) |
                ((unsigned int)(*(unsigned short*)&h1) << 16);
        val.y = (unsigned int)(*(unsigned short*)&h2);
        st[row][xx] = val;
    }
    __syncthreads();

    // ---- B-frags (9 x 16 B, L2-hot) ----
    const bf16x8* bw = (const bf16x8*)(ws + BW1_OFF);
    bf16x8 bfr[9];
    #pragma unroll
    for (int t = 0; t < 9; t++) bfr[t] = bw[t * 64 + l];

    int lm = l & 31, half = l >> 5;
    float bch = (lm < 10) ? ws[B1R_OFF + lm] : 0.f;
    float ach = (lm < 10) ? a1[lm] : 0.f;

    #pragma unroll
    for (int pr = 0; pr < 2; pr++) {
        int ly  = (wv << 2) + (pr << 1);      // local conv row (pair top), even
        int phg = (y0 + ly) >> 1;             // pooled row
        #pragma unroll
        for (int t = 0; t < 2; t++) {
            f32x16 acc0, acc1;
            #pragma unroll
            for (int i = 0; i < 16; i++) { acc0[i] = 0.f; acc1[i] = 0.f; }
            int bx = (t << 5) + lm;           // A pixel-x (local)
            #pragma unroll
            for (int tap = 0; tap < 9; tap++) {
                int kh = tap / 3, kw = tap - kh * 3;
                uint2 q0 = st[ly + kh][bx + kw];
                uint2 q1 = st[ly + kh + 1][bx + kw];
                acc0 = __builtin_amdgcn_mfma_f32_32x32x16_bf16(make_a(q0), bfr[tap], acc0, 0, 0, 0);
                acc1 = __builtin_amdgcn_mfma_f32_32x32x16_bf16(make_a(q1), bfr[tap], acc1, 0, 0, 0);
            }
            // epilogue: bias + PReLU + 2x2 max, all in-lane
            float pv[16];
            #pragma unroll
            for (int r = 0; r < 16; r++) {
                float v0 = acc0[r] + bch; v0 = fmaxf(v0, ach * v0);
                float v1 = acc1[r] + bch; v1 = fmaxf(v1, ach * v1);
                pv[r] = fmaxf(v0, v1);
            }
            if (lm < 10 && phg < PH) {
                size_t rowbase = (((size_t)n * PH + phg) * PH) * 16 + lm;
                #pragma unroll
                for (int q = 0; q < 8; q++) {
                    float pm = fmaxf(pv[2 * q], pv[2 * q + 1]);
                    int pmi = (q & 1) + ((q >> 1) << 2) + (half << 1);
                    int pw  = (x0 >> 1) + (t << 4) + pmi;
                    if (pw < PH)
                        p16[rowbase + (size_t)pw * 16] = __float2bfloat16(pm);
                }
            }
        }
    }
}

// ---------------------------------------------------------------------------
// Stage 2: conv2 3x3 (16pad->16) + bias + PReLU, MFMA 16x16x32 bf16 (R4,
// verified). A = weights (reg-resident), B = pixels -> coalesced NHWC store.
// grid: (6, 90, 16), block 256. No barriers.
// ---------------------------------------------------------------------------
__global__ __launch_bounds__(256)
void conv2_mfma_kernel(const __hip_bfloat16* __restrict__ p16,
                       const float* __restrict__ ws,
                       const float* __restrict__ b2,
                       const float* __restrict__ a2,
                       __hip_bfloat16* __restrict__ c2h) {
    int wv = threadIdx.x >> 6;
    int l  = threadIdx.x & 63;
    int oh  = blockIdx.y * 4 + wv;
    int ow0 = blockIdx.x * 64;
    int n   = blockIdx.z;
    if (oh >= H2) return;

    int pxl = l & 15;
    int q   = l >> 4;
    int taph = q >> 1;
    int choff = (q & 1) << 3;

    const bf16x8* aw = (const bf16x8*)(ws + AW2_OFF);
    bf16x8 afr[5];
    #pragma unroll
    for (int s = 0; s < 5; s++) afr[s] = aw[s * 64 + l];

    bf16x8 zf;
    #pragma unroll
    for (int j = 0; j < 8; j++) zf[j] = 0;

    f32x4 acc[4];
    #pragma unroll
    for (int t = 0; t < 4; t++)
        #pragma unroll
        for (int i = 0; i < 4; i++) acc[t][i] = 0.f;

    #pragma unroll
    for (int s = 0; s < 5; s++) {
        int tap = 2 * s + taph;
        bool real = (tap < 9);
        int kh = tap / 3, kw = tap - kh * 3;
        int ih = oh + kh; if (ih > PH - 1) ih = PH - 1;
        #pragma unroll
        for (int t = 0; t < 4; t++) {
            int iw = ow0 + t * 16 + pxl + kw; if (iw > PH - 1) iw = PH - 1;
            const bf16x8* bp = (const bf16x8*)(p16 + (((size_t)n * PH + ih) * PH + iw) * 16 + choff);
            bf16x8 b = real ? *bp : zf;
            acc[t] = __builtin_amdgcn_mfma_f32_16x16x32_bf16(afr[s], b, acc[t], 0, 0, 0);
        }
    }

    float bb[4], aa[4];
    #pragma unroll
    for (int r = 0; r < 4; r++) { bb[r] = b2[q * 4 + r]; aa[r] = a2[q * 4 + r]; }

    #pragma unroll
    for (int t = 0; t < 4; t++) {
        int px = ow0 + t * 16 + pxl;
        if (px < H2) {
            ushort4v pk;
            #pragma unroll
            for (int r = 0; r < 4; r++) {
                float v = acc[t][r] + bb[r];
                v = v >= 0.f ? v : aa[r] * v;
                __hip_bfloat16 h = __float2bfloat16(v);
                pk[r] = *(unsigned short*)&h;
            }
            *(ushort4v*)(c2h + (((size_t)n * H2 + oh) * H2 + px) * 16 + q * 4) = pk;
        }
    }
}

// ---------------------------------------------------------------------------
// Stage 3: conv3 3x3 (16->32) + PReLU + heads, MFMA 32x32x16 bf16 (R3/R4,
// verified). Heads via stride-33 LDS roundtrip; softmax on 2 logits.
// grid: (12, 45, 16), block 256
// ---------------------------------------------------------------------------
__global__ __launch_bounds__(256, 1)
void conv3_heads_kernel(const __hip_bfloat16* __restrict__ c2h,
                        const float* __restrict__ ws,
                        const float* __restrict__ b3,
                        const float* __restrict__ a3,
                        const float* __restrict__ w41,
                        const float* __restrict__ b41,
                        const float* __restrict__ w42,
                        const float* __restrict__ b42,
                        float* __restrict__ out) {
    int wv = threadIdx.x >> 6;
    int l  = threadIdx.x & 63;
    int ow0 = blockIdx.x * 32;
    int oh0 = blockIdx.y * 8 + wv * 2;
    int n   = blockIdx.z;

    int m    = l & 31;
    int half = l >> 5;
    int choff = half << 3;

    const bf16x8* bw = (const bf16x8*)(ws + BW3_OFF);
    bf16x8 bfr[9];
    #pragma unroll
    for (int t = 0; t < 9; t++) bfr[t] = bw[t * 64 + l];

    f32x16 acc0, acc1;
    #pragma unroll
    for (int i = 0; i < 16; i++) { acc0[i] = 0.f; acc1[i] = 0.f; }

    #pragma unroll
    for (int kh = 0; kh < 3; kh++) {
        int ih0 = oh0 + kh;     if (ih0 > H2 - 1) ih0 = H2 - 1;
        int ih1 = oh0 + 1 + kh; if (ih1 > H2 - 1) ih1 = H2 - 1;
        #pragma unroll
        for (int kw = 0; kw < 3; kw++) {
            int iw = ow0 + m + kw; if (iw > H2 - 1) iw = H2 - 1;
            const bf16x8* a0p = (const bf16x8*)(c2h + ((((size_t)n * H2 + ih0) * H2 + iw) << 4) + choff);
            const bf16x8* a1p = (const bf16x8*)(c2h + ((((size_t)n * H2 + ih1) * H2 + iw) << 4) + choff);
            bf16x8 a0 = *a0p;
            bf16x8 a1 = *a1p;
            int tap = kh * 3 + kw;
            acc0 = __builtin_amdgcn_mfma_f32_32x32x16_bf16(a0, bfr[tap], acc0, 0, 0, 0);
            acc1 = __builtin_amdgcn_mfma_f32_32x32x16_bf16(a1, bfr[tap], acc1, 0, 0, 0);
        }
    }

    __shared__ float hbuf[4][64 * 33];
    float* hb = hbuf[wv];
    float bb = b3[m], aa = a3[m];
    #pragma unroll
    for (int t = 0; t < 2; t++) {
        #pragma unroll
        for (int r = 0; r < 16; r++) {
            int mprime = (r & 3) + ((r >> 2) << 3) + (half << 2);
            float v = (t ? acc1[r] : acc0[r]) + bb;
            v = v >= 0.f ? v : aa * v;
            hb[(t * 32 + mprime) * 33 + m] = v;
        }
    }
    __syncthreads();

    int poh = oh0 + (l >> 5);
    int pow_ = ow0 + (l & 31);
    float h[32];
    #pragma unroll
    for (int c = 0; c < 32; c++) h[c] = hb[l * 33 + c];

    float l0 = b41[0], l1 = b41[1];
    float r0 = b42[0], r1 = b42[1], r2 = b42[2], r3 = b42[3];
    #pragma unroll
    for (int c = 0; c < 32; c++) {
        float hv = h[c];
        l0 = fmaf(hv, w41[c],      l0);
        l1 = fmaf(hv, w41[32 + c], l1);
        r0 = fmaf(hv, w42[c],      r0);
        r1 = fmaf(hv, w42[32 + c], r1);
        r2 = fmaf(hv, w42[64 + c], r2);
        r3 = fmaf(hv, w42[96 + c], r3);
    }
    float mx  = fmaxf(l0, l1);
    float e0 = __expf(l0 - mx), e1 = __expf(l1 - mx);
    float inv = 1.0f / (e0 + e1);

    if (poh < H3 && pow_ < H3) {
        const size_t sp = (size_t)H3 * H3;
        size_t pos = (size_t)poh * H3 + pow_;
        float* reg  = out;
        float* prob = out + (size_t)16 * 4 * sp;
        reg[((size_t)(n * 4 + 0)) * sp + pos] = r0;
        reg[((size_t)(n * 4 + 1)) * sp + pos] = r1;
        reg[((size_t)(n * 4 + 2)) * sp + pos] = r2;
        reg[((size_t)(n * 4 + 3)) * sp + pos] = r3;
        prob[((size_t)(n * 2 + 0)) * sp + pos] = e0 * inv;
        prob[((size_t)(n * 2 + 1)) * sp + pos] = e1 * inv;
    }
}

extern "C" void kernel_launch(void* const* d_in, const int* in_sizes, int n_in,
                              void* d_out, int out_size, void* d_ws, size_t ws_size,
                              hipStream_t stream) {
    const float* x   = (const float*)d_in[0];
    const float* w1  = (const float*)d_in[1];
    const float* b1  = (const float*)d_in[2];
    const float* a1  = (const float*)d_in[3];
    const float* w2  = (const float*)d_in[4];
    const float* b2  = (const float*)d_in[5];
    const float* a2  = (const float*)d_in[6];
    const float* w3  = (const float*)d_in[7];
    const float* b3  = (const float*)d_in[8];
    const float* a3  = (const float*)d_in[9];
    const float* w41 = (const float*)d_in[10];
    const float* b41 = (const float*)d_in[11];
    const float* w42 = (const float*)d_in[12];
    const float* b42 = (const float*)d_in[13];
    float* out = (float*)d_out;
    float* ws  = (float*)d_ws;

    __hip_bfloat16* p16 = (__hip_bfloat16*)(ws + P16_OFF);
    __hip_bfloat16* c2h = (__hip_bfloat16*)(ws + C2H_OFF);

    repack_kernel<<<1, 256, 0, stream>>>(w1, b1, w2, w3, ws);

    {
        dim3 grid((H1 + 63) / 64, (H1 + 15) / 16, 16);
        conv1_mfma_kernel<<<grid, 256, 0, stream>>>(x, ws, a1, p16);
    }
    {
        dim3 grid((H2 + 63) / 64, (H2 + 3) / 4, 16);
        conv2_mfma_kernel<<<grid, 256, 0, stream>>>(p16, ws, b2, a2, c2h);
    }
    {
        dim3 grid((H3 + 31) / 32, (H3 + 7) / 8, 16);
        conv3_heads_kernel<<<grid, 256, 0, stream>>>(c2h, ws, b3, a3,
                                                     w41, b41, w42, b42, out);
    }
}